// Round 1
// baseline (8311.476 us; speedup 1.0000x reference)
//
#include <hip/hip_runtime.h>
#include <math.h>

#define HDIM 2048
#define NTOK 4096
#define NHEAD 16
#define HEADD 128
#define TSEQ 2048
#define BATCH 2

// ---------------- LayerNorm: one block (256 thr) per token row ----------------
__global__ __launch_bounds__(256) void ln_kernel(const float* __restrict__ in,
                                                 const float* __restrict__ scale,
                                                 const float* __restrict__ shift,
                                                 float* __restrict__ out) {
  int row = blockIdx.x;
  int t = threadIdx.x;
  const float4* r4 = (const float4*)(in + (size_t)row * HDIM);
  float4 v0 = r4[t];
  float4 v1 = r4[t + 256];
  float sum = v0.x + v0.y + v0.z + v0.w + v1.x + v1.y + v1.z + v1.w;
  float sq  = v0.x*v0.x + v0.y*v0.y + v0.z*v0.z + v0.w*v0.w +
              v1.x*v1.x + v1.y*v1.y + v1.z*v1.z + v1.w*v1.w;
  // wave reduce (64 lanes)
  for (int o = 32; o > 0; o >>= 1) {
    sum += __shfl_down(sum, o);
    sq  += __shfl_down(sq, o);
  }
  __shared__ float red[8];
  __shared__ float stat[2];
  int lane = t & 63, w = t >> 6;
  if (lane == 0) { red[w] = sum; red[4 + w] = sq; }
  __syncthreads();
  if (t == 0) {
    float s = red[0] + red[1] + red[2] + red[3];
    float q = red[4] + red[5] + red[6] + red[7];
    float mean = s / HDIM;
    float var = q / HDIM - mean * mean;
    stat[0] = mean;
    stat[1] = rsqrtf(var + 1e-5f);
  }
  __syncthreads();
  float mean = stat[0], rstd = stat[1];
  const float4* sc4 = (const float4*)scale;
  const float4* sh4 = (const float4*)shift;
  float4* o4 = (float4*)(out + (size_t)row * HDIM);
  float4 s0 = sc4[t], s1 = sc4[t + 256];
  float4 h0 = sh4[t], h1 = sh4[t + 256];
  float4 w0, w1;
  w0.x = s0.x * ((v0.x - mean) * rstd) + h0.x;
  w0.y = s0.y * ((v0.y - mean) * rstd) + h0.y;
  w0.z = s0.z * ((v0.z - mean) * rstd) + h0.z;
  w0.w = s0.w * ((v0.w - mean) * rstd) + h0.w;
  w1.x = s1.x * ((v1.x - mean) * rstd) + h1.x;
  w1.y = s1.y * ((v1.y - mean) * rstd) + h1.y;
  w1.z = s1.z * ((v1.z - mean) * rstd) + h1.z;
  w1.w = s1.w * ((v1.w - mean) * rstd) + h1.w;
  o4[t] = w0;
  o4[t + 256] = w1;
}

// ---------------- fp32 tiled GEMM: C[M,N] = A[M,K] @ B[K,N] (+bias, gelu, resid) ----------------
#define BM 64
#define BN 64
#define BKT 16
#define LPAD 68

__device__ __forceinline__ float gelu_tanh_f(float x) {
  float z = 0.7978845608028654f * (x + 0.044715f * x * x * x);
  float e = __expf(2.f * z);
  float th = 1.f - 2.f / (e + 1.f);
  return 0.5f * x * (1.f + th);
}

__global__ __launch_bounds__(256) void gemm_kernel(const float* __restrict__ A,
                                                   const float* __restrict__ B,
                                                   float* __restrict__ C,
                                                   const float* __restrict__ bias,
                                                   const float* __restrict__ resid,
                                                   int M, int N, int K, int act_gelu) {
  __shared__ __align__(16) float As[BKT][LPAD];
  __shared__ __align__(16) float Bs[BKT][LPAD];
  int tid = threadIdx.x;
  int m0 = blockIdx.y * BM, n0 = blockIdx.x * BN;
  int tx = tid & 15, ty = tid >> 4;
  int a_k = tid & 15, a_m = tid >> 4;   // A-load: k = a_k, m = a_m + i*16
  int b_n = tid & 63, b_k = tid >> 6;   // B-load: n = b_n, k = b_k + i*4
  float c[4][4] = {};
  for (int k0 = 0; k0 < K; k0 += BKT) {
#pragma unroll
    for (int i = 0; i < 4; i++)
      As[a_k][a_m + i * 16] = A[(size_t)(m0 + a_m + i * 16) * K + k0 + a_k];
#pragma unroll
    for (int i = 0; i < 4; i++)
      Bs[b_k + i * 4][b_n] = B[(size_t)(k0 + b_k + i * 4) * N + n0 + b_n];
    __syncthreads();
#pragma unroll
    for (int kk = 0; kk < BKT; kk++) {
      float4 a = *(const float4*)&As[kk][ty * 4];
      float4 b = *(const float4*)&Bs[kk][tx * 4];
      float av[4] = {a.x, a.y, a.z, a.w};
      float bv[4] = {b.x, b.y, b.z, b.w};
#pragma unroll
      for (int i = 0; i < 4; i++)
#pragma unroll
        for (int j = 0; j < 4; j++)
          c[i][j] += av[i] * bv[j];
    }
    __syncthreads();
  }
#pragma unroll
  for (int i = 0; i < 4; i++) {
    int m = m0 + ty * 4 + i;
#pragma unroll
    for (int j = 0; j < 4; j++) {
      int n = n0 + tx * 4 + j;
      float v = c[i][j];
      if (bias) v += bias[n];
      if (act_gelu) v = gelu_tanh_f(v);
      if (resid) v += resid[(size_t)m * N + n];
      C[(size_t)m * N + n] = v;
    }
  }
}

// ---------------- causal flash attention, fp32 ----------------
// grid: (T/32, NHEAD, BATCH), 256 threads
#define BQ 32
#define BKEY 32
#define KPAD 132

__global__ __launch_bounds__(256) void attn_kernel(const float* __restrict__ Q,
                                                   const float* __restrict__ K,
                                                   const float* __restrict__ V,
                                                   float* __restrict__ O) {
  __shared__ __align__(16) float Qs[BQ][KPAD];
  __shared__ __align__(16) float Ks[BKEY][KPAD];
  __shared__ __align__(16) float Vs[BKEY][KPAD];
  __shared__ float Ps[BQ][BKEY + 1];
  __shared__ float mrow[BQ], lrow[BQ], arow[BQ];

  int tid = threadIdx.x;
  int qt = blockIdx.x, hh = blockIdx.y, bb = blockIdx.z;
  int q0 = qt * BQ;
  size_t base = ((size_t)bb * TSEQ) * HDIM + (size_t)hh * HEADD;

#pragma unroll
  for (int i = 0; i < 4; i++) {
    int idx = tid + i * 256;
    int r = idx >> 5, c4 = idx & 31;
    *(float4*)&Qs[r][c4 * 4] = *(const float4*)&Q[base + (size_t)(q0 + r) * HDIM + c4 * 4];
  }
  if (tid < BQ) { mrow[tid] = -3.0e38f; lrow[tid] = 0.f; }
  float o[16] = {};
  int oq = tid >> 3, od = (tid & 7) * 16;
  int sq = tid >> 3, sk = (tid & 7) * 4;
  const float scl = 0.08838834764831845f;  // 1/sqrt(128)
  __syncthreads();

  for (int kt = 0; kt <= qt; kt++) {
    int k0 = kt * BKEY;
#pragma unroll
    for (int i = 0; i < 4; i++) {
      int idx = tid + i * 256;
      int r = idx >> 5, c4 = idx & 31;
      *(float4*)&Ks[r][c4 * 4] = *(const float4*)&K[base + (size_t)(k0 + r) * HDIM + c4 * 4];
      *(float4*)&Vs[r][c4 * 4] = *(const float4*)&V[base + (size_t)(k0 + r) * HDIM + c4 * 4];
    }
    __syncthreads();

    // scores: each thread computes 4 scores (q=sq, k=sk..sk+3)
    float s[4] = {0.f, 0.f, 0.f, 0.f};
    for (int d4 = 0; d4 < 32; d4++) {
      float4 qv = *(const float4*)&Qs[sq][d4 * 4];
#pragma unroll
      for (int j = 0; j < 4; j++) {
        float4 kv = *(const float4*)&Ks[sk + j][d4 * 4];
        s[j] += qv.x * kv.x + qv.y * kv.y + qv.z * kv.z + qv.w * kv.w;
      }
    }
#pragma unroll
    for (int j = 0; j < 4; j++) {
      int kg = k0 + sk + j, qg = q0 + sq;
      Ps[sq][sk + j] = (kg <= qg) ? s[j] * scl : -3.0e38f;
    }
    __syncthreads();

    // online softmax: one thread per query row
    if (tid < BQ) {
      float m_old = mrow[tid];
      float mt = m_old;
      for (int k = 0; k < BKEY; k++) mt = fmaxf(mt, Ps[tid][k]);
      float alpha = __expf(m_old - mt);
      float lsum = 0.f;
      for (int k = 0; k < BKEY; k++) {
        float p = __expf(Ps[tid][k] - mt);
        Ps[tid][k] = p;
        lsum += p;
      }
      mrow[tid] = mt;
      lrow[tid] = lrow[tid] * alpha + lsum;
      arow[tid] = alpha;
    }
    __syncthreads();

    // O update: thread owns (q=oq, d=od..od+15)
    float alpha = arow[oq];
#pragma unroll
    for (int j = 0; j < 16; j++) o[j] *= alpha;
    for (int k = 0; k < BKEY; k++) {
      float p = Ps[oq][k];
#pragma unroll
      for (int j4 = 0; j4 < 4; j4++) {
        float4 vv = *(const float4*)&Vs[k][od + j4 * 4];
        o[j4 * 4 + 0] += p * vv.x;
        o[j4 * 4 + 1] += p * vv.y;
        o[j4 * 4 + 2] += p * vv.z;
        o[j4 * 4 + 3] += p * vv.w;
      }
    }
    __syncthreads();
  }

  float inv = 1.f / lrow[oq];
  size_t obase = base + (size_t)(q0 + oq) * HDIM + od;
#pragma unroll
  for (int j4 = 0; j4 < 4; j4++) {
    float4 w;
    w.x = o[j4 * 4 + 0] * inv;
    w.y = o[j4 * 4 + 1] * inv;
    w.z = o[j4 * 4 + 2] * inv;
    w.w = o[j4 * 4 + 3] * inv;
    *(float4*)&O[obase + j4 * 4] = w;
  }
}

// ---------------- launch ----------------
extern "C" void kernel_launch(void* const* d_in, const int* in_sizes, int n_in,
                              void* d_out, int out_size, void* d_ws, size_t ws_size,
                              hipStream_t stream) {
  const float* x         = (const float*)d_in[0];
  const float* wq        = (const float*)d_in[1];
  const float* wk        = (const float*)d_in[2];
  const float* wv        = (const float*)d_in[3];
  const float* wo        = (const float*)d_in[4];
  const float* ln1_scale = (const float*)d_in[5];
  const float* ln1_shift = (const float*)d_in[6];
  const float* ln2_scale = (const float*)d_in[7];
  const float* ln2_shift = (const float*)d_in[8];
  const float* w1        = (const float*)d_in[9];
  const float* b1        = (const float*)d_in[10];
  const float* w2        = (const float*)d_in[11];
  const float* b2        = (const float*)d_in[12];
  float* out = (float*)d_out;

  char* ws = (char*)d_ws;
  const size_t SZ = (size_t)NTOK * HDIM * sizeof(float);  // 32 MiB
  float* r0 = (float*)(ws);            // h1 -> attn -> h2
  float* r1 = (float*)(ws + SZ);       // Q -> x2
  float* r2 = (float*)(ws + 2 * SZ);   // K
  float* r3 = (float*)(ws + 3 * SZ);   // V
  float* a1 = (float*)(ws + 2 * SZ);   // FFN hidden [4096, 8192] = 128 MiB (aliases K,V — dead)

  dim3 blk(256);
  // LN1: x -> h1 (r0)
  ln_kernel<<<NTOK, blk, 0, stream>>>(x, ln1_scale, ln1_shift, r0);
  // Q,K,V GEMMs
  gemm_kernel<<<dim3(HDIM / BN, NTOK / BM), blk, 0, stream>>>(r0, wq, r1, nullptr, nullptr, NTOK, HDIM, HDIM, 0);
  gemm_kernel<<<dim3(HDIM / BN, NTOK / BM), blk, 0, stream>>>(r0, wk, r2, nullptr, nullptr, NTOK, HDIM, HDIM, 0);
  gemm_kernel<<<dim3(HDIM / BN, NTOK / BM), blk, 0, stream>>>(r0, wv, r3, nullptr, nullptr, NTOK, HDIM, HDIM, 0);
  // attention -> r0 (h1 dead)
  attn_kernel<<<dim3(TSEQ / BQ, NHEAD, BATCH), blk, 0, stream>>>(r1, r2, r3, r0);
  // x2 = x + attn @ wo -> r1 (Q dead)
  gemm_kernel<<<dim3(HDIM / BN, NTOK / BM), blk, 0, stream>>>(r0, wo, r1, nullptr, x, NTOK, HDIM, HDIM, 0);
  // LN2: x2 -> h2 (r0, attn dead)
  ln_kernel<<<NTOK, blk, 0, stream>>>(r1, ln2_scale, ln2_shift, r0);
  // a1 = gelu(h2 @ w1 + b1) -> a1 (K,V dead)
  gemm_kernel<<<dim3(4 * HDIM / BN, NTOK / BM), blk, 0, stream>>>(r0, w1, a1, b1, nullptr, NTOK, 4 * HDIM, HDIM, 1);
  // out = x2 + a1 @ w2 + b2
  gemm_kernel<<<dim3(HDIM / BN, NTOK / BM), blk, 0, stream>>>(a1, w2, out, b2, r1, NTOK, HDIM, 4 * HDIM, 0);
}

// Round 2
// 2173.614 us; speedup vs baseline: 3.8238x; 3.8238x over previous
//
#include <hip/hip_runtime.h>
#include <math.h>

#define HDIM 2048
#define NTOK 4096
#define NHEAD 16
#define HEADD 128
#define TSEQ 2048
#define NBATCH 2
#define QKVW 6144  // merged QKV row width (floats)

typedef float f32x4 __attribute__((ext_vector_type(4)));
typedef short bf16x8 __attribute__((ext_vector_type(8)));

__device__ __forceinline__ unsigned short f2bf(float f) {
  union { float f; unsigned u; } v; v.f = f;
  unsigned r = v.u + 0x7FFFu + ((v.u >> 16) & 1u);
  return (unsigned short)(r >> 16);
}

__device__ __forceinline__ float gelu_tanh_f(float x) {
  float z = 0.7978845608028654f * (x + 0.044715f * x * x * x);
  float e = __expf(2.f * z);
  float th = 1.f - 2.f / (e + 1.f);
  return 0.5f * x * (1.f + th);
}

// ---------------- LayerNorm: fp32 in, bf16 out. one block per token ----------------
__global__ __launch_bounds__(256) void ln_kernel(const float* __restrict__ in,
                                                 const float* __restrict__ scale,
                                                 const float* __restrict__ shift,
                                                 unsigned short* __restrict__ out) {
  int row = blockIdx.x;
  int t = threadIdx.x;
  const float4* r4 = (const float4*)(in + (size_t)row * HDIM);
  float4 v0 = r4[t];
  float4 v1 = r4[t + 256];
  float sum = v0.x + v0.y + v0.z + v0.w + v1.x + v1.y + v1.z + v1.w;
  float sq  = v0.x*v0.x + v0.y*v0.y + v0.z*v0.z + v0.w*v0.w +
              v1.x*v1.x + v1.y*v1.y + v1.z*v1.z + v1.w*v1.w;
  for (int o = 32; o > 0; o >>= 1) {
    sum += __shfl_down(sum, o);
    sq  += __shfl_down(sq, o);
  }
  __shared__ float red[8];
  __shared__ float stat[2];
  int lane = t & 63, w = t >> 6;
  if (lane == 0) { red[w] = sum; red[4 + w] = sq; }
  __syncthreads();
  if (t == 0) {
    float s = red[0] + red[1] + red[2] + red[3];
    float q = red[4] + red[5] + red[6] + red[7];
    float mean = s / HDIM;
    float var = q / HDIM - mean * mean;
    stat[0] = mean;
    stat[1] = rsqrtf(var + 1e-5f);
  }
  __syncthreads();
  float mean = stat[0], rstd = stat[1];
  const float4* sc4 = (const float4*)scale;
  const float4* sh4 = (const float4*)shift;
  float4 s0 = sc4[t], s1 = sc4[t + 256];
  float4 h0 = sh4[t], h1 = sh4[t + 256];
  ushort4 a, b;
  a.x = f2bf(s0.x * ((v0.x - mean) * rstd) + h0.x);
  a.y = f2bf(s0.y * ((v0.y - mean) * rstd) + h0.y);
  a.z = f2bf(s0.z * ((v0.z - mean) * rstd) + h0.z);
  a.w = f2bf(s0.w * ((v0.w - mean) * rstd) + h0.w);
  b.x = f2bf(s1.x * ((v1.x - mean) * rstd) + h1.x);
  b.y = f2bf(s1.y * ((v1.y - mean) * rstd) + h1.y);
  b.z = f2bf(s1.z * ((v1.z - mean) * rstd) + h1.z);
  b.w = f2bf(s1.w * ((v1.w - mean) * rstd) + h1.w);
  *(ushort4*)&out[(size_t)row * HDIM + t * 4] = a;
  *(ushort4*)&out[(size_t)row * HDIM + 1024 + t * 4] = b;
}

// ---------------- cast + transpose: W[K,N] fp32 -> Wt[N,K] bf16 ----------------
__global__ __launch_bounds__(256) void castT_kernel(const float* __restrict__ W,
                                                    unsigned short* __restrict__ Wt,
                                                    int K, int N) {
  __shared__ float T[64][65];
  int k0 = blockIdx.x * 64, n0 = blockIdx.y * 64;
  int c = threadIdx.x & 15, r = threadIdx.x >> 4;
#pragma unroll
  for (int p = 0; p < 4; p++) {
    int kr = r + p * 16;
    float4 v = *(const float4*)&W[(size_t)(k0 + kr) * N + n0 + c * 4];
    T[kr][c * 4 + 0] = v.x; T[kr][c * 4 + 1] = v.y;
    T[kr][c * 4 + 2] = v.z; T[kr][c * 4 + 3] = v.w;
  }
  __syncthreads();
#pragma unroll
  for (int p = 0; p < 4; p++) {
    int nr = r + p * 16;
    ushort4 o;
    o.x = f2bf(T[c * 4 + 0][nr]);
    o.y = f2bf(T[c * 4 + 1][nr]);
    o.z = f2bf(T[c * 4 + 2][nr]);
    o.w = f2bf(T[c * 4 + 3][nr]);
    *(ushort4*)&Wt[(size_t)(n0 + nr) * K + k0 + c * 4] = o;
  }
}

// ---------------- bf16 MFMA GEMM: C[M,N] = A[M,K] @ Bt[N,K]^T ----------------
#define GLL16(g, l) __builtin_amdgcn_global_load_lds( \
    (const __attribute__((address_space(1))) unsigned int*)(g), \
    (__attribute__((address_space(3))) unsigned int*)(l), 16, 0, 0)

__global__ __launch_bounds__(256) void gemm_bt(const unsigned short* __restrict__ A,
                                               const unsigned short* __restrict__ Bt,
                                               float* __restrict__ Cf,
                                               unsigned short* __restrict__ Cb,
                                               const float* __restrict__ bias,
                                               const float* __restrict__ resid,
                                               int M, int N, int K, int act_gelu) {
  __shared__ unsigned short ldsA[128 * 32];
  __shared__ unsigned short ldsB[128 * 32];
  int tid = threadIdx.x;
  int w = tid >> 6, lane = tid & 63;
  int lm = lane & 15, q = lane >> 4;
  int wm = w & 1, wn = w >> 1;
  int m0 = blockIdx.y * 128, n0 = blockIdx.x * 128;

  // staging decode. LDS tile: 128 rows x 64B; 16B position kb in row holds
  // global k-block (kb ^ ((row>>1)&3)) -> only free 2-way bank aliasing on reads.
  int row0, row1, kbg0, kbg1;
  {
    int o = w * 2048 + lane * 16;
    row0 = o >> 6; kbg0 = ((o >> 4) & 3) ^ ((row0 >> 1) & 3);
    o += 1024;
    row1 = o >> 6; kbg1 = ((o >> 4) & 3) ^ ((row1 >> 1) & 3);
  }
  const unsigned short* pa0 = A  + (size_t)(m0 + row0) * K + kbg0 * 8;
  const unsigned short* pa1 = A  + (size_t)(m0 + row1) * K + kbg1 * 8;
  const unsigned short* pb0 = Bt + (size_t)(n0 + row0) * K + kbg0 * 8;
  const unsigned short* pb1 = Bt + (size_t)(n0 + row1) * K + kbg1 * 8;
  unsigned short* la0 = ldsA + w * 1024;
  unsigned short* la1 = ldsA + w * 1024 + 512;
  unsigned short* lb0 = ldsB + w * 1024;
  unsigned short* lb1 = ldsB + w * 1024 + 512;

  f32x4 acc[4][4] = {};
  int s = (lm >> 1) & 3;
  int aoff[4], boff[4];
#pragma unroll
  for (int t = 0; t < 4; t++) {
    aoff[t] = ((wm * 64 + t * 16 + lm) << 5) + ((q ^ s) << 3);  // ushort units
    boff[t] = ((wn * 64 + t * 16 + lm) << 5) + ((q ^ s) << 3);
  }

  for (int k0 = 0; k0 < K; k0 += 32) {
    GLL16(pa0 + k0, la0);
    GLL16(pa1 + k0, la1);
    GLL16(pb0 + k0, lb0);
    GLL16(pb1 + k0, lb1);
    __syncthreads();
    bf16x8 af[4], bfv[4];
#pragma unroll
    for (int t = 0; t < 4; t++) af[t] = *(const bf16x8*)(ldsA + aoff[t]);
#pragma unroll
    for (int t = 0; t < 4; t++) bfv[t] = *(const bf16x8*)(ldsB + boff[t]);
#pragma unroll
    for (int mi = 0; mi < 4; mi++)
#pragma unroll
      for (int ni = 0; ni < 4; ni++)
        acc[mi][ni] = __builtin_amdgcn_mfma_f32_16x16x32_bf16(af[mi], bfv[ni], acc[mi][ni], 0, 0, 0);
    __syncthreads();
  }

#pragma unroll
  for (int ni = 0; ni < 4; ni++) {
    int n = n0 + wn * 64 + ni * 16 + lm;
    float bv = bias ? bias[n] : 0.f;
#pragma unroll
    for (int mi = 0; mi < 4; mi++) {
#pragma unroll
      for (int r = 0; r < 4; r++) {
        int m = m0 + wm * 64 + mi * 16 + q * 4 + r;
        float v = acc[mi][ni][r] + bv;
        if (act_gelu) v = gelu_tanh_f(v);
        if (resid) v += resid[(size_t)m * N + n];
        if (Cb) Cb[(size_t)m * N + n] = f2bf(v);
        else Cf[(size_t)m * N + n] = v;
      }
    }
  }
}

// ---------------- causal flash attention, fp32 compute, bf16 out ----------------
#define BQ 32
#define BKEY 32
#define KP 132

__global__ __launch_bounds__(256) void attn_kernel(const float* __restrict__ QKV,
                                                   unsigned short* __restrict__ O) {
  __shared__ float Qs[BQ][KP];
  __shared__ float Ks[BKEY][KP];
  __shared__ float Vs[BKEY][KP];
  __shared__ float Ps[BQ][BKEY + 1];
  __shared__ float mrow[BQ], lrow[BQ], arow[BQ];
  int tid = threadIdx.x;
  int qt = blockIdx.x, hh = blockIdx.y, bb = blockIdx.z;
  int q0 = qt * BQ;
  size_t base = (size_t)bb * TSEQ * QKVW + (size_t)hh * HEADD;
  const float* Qp = QKV + base;
  const float* Kp = QKV + base + HDIM;
  const float* Vp = QKV + base + 2 * HDIM;
#pragma unroll
  for (int i = 0; i < 4; i++) {
    int idx = tid + i * 256;
    int r = idx >> 5, c4 = idx & 31;
    *(float4*)&Qs[r][c4 * 4] = *(const float4*)&Qp[(size_t)(q0 + r) * QKVW + c4 * 4];
  }
  if (tid < BQ) { mrow[tid] = -3.0e38f; lrow[tid] = 0.f; }
  float o[16] = {};
  int vq = tid & 31, vc = tid >> 5;  // PV mapping: Vs reads broadcast
  int sq = tid >> 3, j8 = tid & 7;   // scores/softmax: 8 lanes/row, k stride 8
  const float scl = 0.08838834764831845f;
  __syncthreads();

  for (int kt = 0; kt <= qt; kt++) {
    int k0 = kt * BKEY;
#pragma unroll
    for (int i = 0; i < 4; i++) {
      int idx = tid + i * 256;
      int r = idx >> 5, c4 = idx & 31;
      *(float4*)&Ks[r][c4 * 4] = *(const float4*)&Kp[(size_t)(k0 + r) * QKVW + c4 * 4];
      *(float4*)&Vs[r][c4 * 4] = *(const float4*)&Vp[(size_t)(k0 + r) * QKVW + c4 * 4];
    }
    __syncthreads();

    float sv[4] = {0.f, 0.f, 0.f, 0.f};
    for (int d4 = 0; d4 < 32; d4++) {
      float4 qv = *(const float4*)&Qs[sq][d4 * 4];
#pragma unroll
      for (int jj = 0; jj < 4; jj++) {
        float4 kv = *(const float4*)&Ks[j8 + jj * 8][d4 * 4];
        sv[jj] += qv.x * kv.x + qv.y * kv.y + qv.z * kv.z + qv.w * kv.w;
      }
    }
    float mloc = -3.0e38f;
#pragma unroll
    for (int jj = 0; jj < 4; jj++) {
      int kg = k0 + j8 + jj * 8;
      sv[jj] = (kg <= q0 + sq) ? sv[jj] * scl : -3.0e38f;
      mloc = fmaxf(mloc, sv[jj]);
    }
#pragma unroll
    for (int d = 1; d < 8; d <<= 1) mloc = fmaxf(mloc, __shfl_xor(mloc, d));
    float m_old = mrow[sq];
    float mt = fmaxf(m_old, mloc);
    float lloc = 0.f;
#pragma unroll
    for (int jj = 0; jj < 4; jj++) {
      float p = __expf(sv[jj] - mt);
      Ps[sq][j8 + jj * 8] = p;
      lloc += p;
    }
#pragma unroll
    for (int d = 1; d < 8; d <<= 1) lloc += __shfl_xor(lloc, d);
    if (j8 == 0) {
      float alpha = __expf(m_old - mt);
      mrow[sq] = mt;
      lrow[sq] = lrow[sq] * alpha + lloc;
      arow[sq] = alpha;
    }
    __syncthreads();

    float alpha = arow[vq];
#pragma unroll
    for (int jj = 0; jj < 16; jj++) o[jj] *= alpha;
    for (int k = 0; k < BKEY; k++) {
      float p = Ps[vq][k];
#pragma unroll
      for (int j4 = 0; j4 < 4; j4++) {
        float4 vv = *(const float4*)&Vs[k][vc * 16 + j4 * 4];
        o[j4 * 4 + 0] += p * vv.x;
        o[j4 * 4 + 1] += p * vv.y;
        o[j4 * 4 + 2] += p * vv.z;
        o[j4 * 4 + 3] += p * vv.w;
      }
    }
    __syncthreads();
  }

  float inv = 1.f / lrow[vq];
#pragma unroll
  for (int jj = 0; jj < 16; jj++) Qs[vq][vc * 16 + jj] = o[jj] * inv;
  __syncthreads();
  size_t ob = ((size_t)bb * TSEQ + q0 + sq) * HDIM + (size_t)hh * HEADD + j8 * 16;
#pragma unroll
  for (int g = 0; g < 4; g++) {
    float4 vv = *(const float4*)&Qs[sq][j8 * 16 + g * 4];
    ushort4 u;
    u.x = f2bf(vv.x); u.y = f2bf(vv.y); u.z = f2bf(vv.z); u.w = f2bf(vv.w);
    *(ushort4*)&O[ob + g * 4] = u;
  }
}

// ---------------- launch ----------------
extern "C" void kernel_launch(void* const* d_in, const int* in_sizes, int n_in,
                              void* d_out, int out_size, void* d_ws, size_t ws_size,
                              hipStream_t stream) {
  const float* x         = (const float*)d_in[0];
  const float* wq        = (const float*)d_in[1];
  const float* wk        = (const float*)d_in[2];
  const float* wv        = (const float*)d_in[3];
  const float* wo        = (const float*)d_in[4];
  const float* ln1_scale = (const float*)d_in[5];
  const float* ln1_shift = (const float*)d_in[6];
  const float* ln2_scale = (const float*)d_in[7];
  const float* ln2_shift = (const float*)d_in[8];
  const float* w1        = (const float*)d_in[9];
  const float* b1        = (const float*)d_in[10];
  const float* w2        = (const float*)d_in[11];
  const float* b2        = (const float*)d_in[12];

  char* ws = (char*)d_ws;
  const size_t MB = 1ull << 20;
  unsigned short* h1    = (unsigned short*)(ws);             // [0,16) dead before x2
  float*          x2    = (float*)(ws);                      // [0,32)
  float*          qkv   = (float*)(ws + 32 * MB);            // [32,128) dead after attn
  unsigned short* h2    = (unsigned short*)(ws + 32 * MB);   // [32,48) after qkv dead
  unsigned short* w1T   = (unsigned short*)(ws + 64 * MB);   // [64,96) after attn
  unsigned short* w2T   = (unsigned short*)(ws + 96 * MB);   // [96,128) after attn
  unsigned short* wqT   = (unsigned short*)(ws + 128 * MB);  // [128,152): wq,wk,wv contiguous
  unsigned short* wkT   = (unsigned short*)(ws + 136 * MB);
  unsigned short* wvT   = (unsigned short*)(ws + 144 * MB);
  unsigned short* woT   = (unsigned short*)(ws + 152 * MB);  // [152,160)
  unsigned short* attnO = (unsigned short*)(ws + 160 * MB);  // [160,176) dead after proj
  unsigned short* a1    = (unsigned short*)(ws + 128 * MB);  // [128,192) FFN1 out

  dim3 blk(256);
  ln_kernel<<<NTOK, blk, 0, stream>>>(x, ln1_scale, ln1_shift, h1);
  castT_kernel<<<dim3(32, 32), blk, 0, stream>>>(wq, wqT, 2048, 2048);
  castT_kernel<<<dim3(32, 32), blk, 0, stream>>>(wk, wkT, 2048, 2048);
  castT_kernel<<<dim3(32, 32), blk, 0, stream>>>(wv, wvT, 2048, 2048);
  castT_kernel<<<dim3(32, 32), blk, 0, stream>>>(wo, woT, 2048, 2048);
  // merged QKV: qkv[4096][6144] = h1 @ [wq|wk|wv]
  gemm_bt<<<dim3(6144 / 128, 4096 / 128), blk, 0, stream>>>(
      h1, wqT, qkv, nullptr, nullptr, nullptr, 4096, 6144, 2048, 0);
  attn_kernel<<<dim3(TSEQ / BQ, NHEAD, NBATCH), blk, 0, stream>>>(qkv, attnO);
  castT_kernel<<<dim3(32, 128), blk, 0, stream>>>(w1, w1T, 2048, 8192);
  castT_kernel<<<dim3(128, 32), blk, 0, stream>>>(w2, w2T, 8192, 2048);
  gemm_bt<<<dim3(2048 / 128, 4096 / 128), blk, 0, stream>>>(
      attnO, woT, x2, nullptr, nullptr, x, 4096, 2048, 2048, 0);
  ln_kernel<<<NTOK, blk, 0, stream>>>(x2, ln2_scale, ln2_shift, h2);
  gemm_bt<<<dim3(8192 / 128, 4096 / 128), blk, 0, stream>>>(
      h2, w1T, nullptr, a1, b1, nullptr, 4096, 8192, 2048, 1);
  gemm_bt<<<dim3(2048 / 128, 4096 / 128), blk, 0, stream>>>(
      a1, w2T, (float*)d_out, nullptr, b2, x2, 4096, 2048, 8192, 0);
}

// Round 3
// 1095.492 us; speedup vs baseline: 7.5870x; 1.9841x over previous
//
#include <hip/hip_runtime.h>
#include <math.h>

#define HDIM 2048
#define NTOK 4096
#define NHEAD 16
#define HEADD 128
#define TSEQ 2048
#define NBATCH 2

typedef float f32x4 __attribute__((ext_vector_type(4)));
typedef short bf16x8 __attribute__((ext_vector_type(8)));

__device__ __forceinline__ unsigned short f2bf(float f) {
  union { float f; unsigned u; } v; v.f = f;
  unsigned r = v.u + 0x7FFFu + ((v.u >> 16) & 1u);
  return (unsigned short)(r >> 16);
}

__device__ __forceinline__ float gelu_tanh_f(float x) {
  float z = 0.7978845608028654f * (x + 0.044715f * x * x * x);
  float e = __expf(2.f * z);
  float th = 1.f - 2.f / (e + 1.f);
  return 0.5f * x * (1.f + th);
}

#define GLL16(g, l) __builtin_amdgcn_global_load_lds( \
    (const __attribute__((address_space(1))) unsigned int*)(g), \
    (__attribute__((address_space(3))) unsigned int*)(l), 16, 0, 0)

// ---------------- LayerNorm: fp32 in, bf16 out. one block per token ----------------
__global__ __launch_bounds__(256) void ln_kernel(const float* __restrict__ in,
                                                 const float* __restrict__ scale,
                                                 const float* __restrict__ shift,
                                                 unsigned short* __restrict__ out) {
  int row = blockIdx.x;
  int t = threadIdx.x;
  const float4* r4 = (const float4*)(in + (size_t)row * HDIM);
  float4 v0 = r4[t];
  float4 v1 = r4[t + 256];
  float sum = v0.x + v0.y + v0.z + v0.w + v1.x + v1.y + v1.z + v1.w;
  float sq  = v0.x*v0.x + v0.y*v0.y + v0.z*v0.z + v0.w*v0.w +
              v1.x*v1.x + v1.y*v1.y + v1.z*v1.z + v1.w*v1.w;
  for (int o = 32; o > 0; o >>= 1) {
    sum += __shfl_down(sum, o);
    sq  += __shfl_down(sq, o);
  }
  __shared__ float red[8];
  __shared__ float stat[2];
  int lane = t & 63, w = t >> 6;
  if (lane == 0) { red[w] = sum; red[4 + w] = sq; }
  __syncthreads();
  if (t == 0) {
    float s = red[0] + red[1] + red[2] + red[3];
    float q = red[4] + red[5] + red[6] + red[7];
    float mean = s / HDIM;
    float var = q / HDIM - mean * mean;
    stat[0] = mean;
    stat[1] = rsqrtf(var + 1e-5f);
  }
  __syncthreads();
  float mean = stat[0], rstd = stat[1];
  const float4* sc4 = (const float4*)scale;
  const float4* sh4 = (const float4*)shift;
  float4 s0 = sc4[t], s1 = sc4[t + 256];
  float4 h0 = sh4[t], h1 = sh4[t + 256];
  ushort4 a, b;
  a.x = f2bf(s0.x * ((v0.x - mean) * rstd) + h0.x);
  a.y = f2bf(s0.y * ((v0.y - mean) * rstd) + h0.y);
  a.z = f2bf(s0.z * ((v0.z - mean) * rstd) + h0.z);
  a.w = f2bf(s0.w * ((v0.w - mean) * rstd) + h0.w);
  b.x = f2bf(s1.x * ((v1.x - mean) * rstd) + h1.x);
  b.y = f2bf(s1.y * ((v1.y - mean) * rstd) + h1.y);
  b.z = f2bf(s1.z * ((v1.z - mean) * rstd) + h1.z);
  b.w = f2bf(s1.w * ((v1.w - mean) * rstd) + h1.w);
  *(ushort4*)&out[(size_t)row * HDIM + t * 4] = a;
  *(ushort4*)&out[(size_t)row * HDIM + 1024 + t * 4] = b;
}

// ---------------- cast + transpose: W[K,N] fp32 -> Wt[N,K] bf16 ----------------
__global__ __launch_bounds__(256) void castT_kernel(const float* __restrict__ W,
                                                    unsigned short* __restrict__ Wt,
                                                    int K, int N) {
  __shared__ float T[64][65];
  int k0 = blockIdx.x * 64, n0 = blockIdx.y * 64;
  int c = threadIdx.x & 15, r = threadIdx.x >> 4;
#pragma unroll
  for (int p = 0; p < 4; p++) {
    int kr = r + p * 16;
    float4 v = *(const float4*)&W[(size_t)(k0 + kr) * N + n0 + c * 4];
    T[kr][c * 4 + 0] = v.x; T[kr][c * 4 + 1] = v.y;
    T[kr][c * 4 + 2] = v.z; T[kr][c * 4 + 3] = v.w;
  }
  __syncthreads();
#pragma unroll
  for (int p = 0; p < 4; p++) {
    int nr = r + p * 16;
    ushort4 o;
    o.x = f2bf(T[c * 4 + 0][nr]);
    o.y = f2bf(T[c * 4 + 1][nr]);
    o.z = f2bf(T[c * 4 + 2][nr]);
    o.w = f2bf(T[c * 4 + 3][nr]);
    *(ushort4*)&Wt[(size_t)(n0 + nr) * K + k0 + c * 4] = o;
  }
}

// ---------------- bf16 MFMA GEMM: C[M,N] = A[M,K] @ Bt[N,K]^T ----------------
// qkv_mode: scatter epilogue to per-head Q[b,h,t,d], K[b,h,t,d], Vt[b,h,d,t] bf16.
__global__ __launch_bounds__(256) void gemm_bt(const unsigned short* __restrict__ A,
                                               const unsigned short* __restrict__ Bt,
                                               float* __restrict__ Cf,
                                               unsigned short* __restrict__ Cb,
                                               const float* __restrict__ bias,
                                               const float* __restrict__ resid,
                                               int M, int N, int K, int act_gelu,
                                               int qkv_mode,
                                               unsigned short* __restrict__ Qo,
                                               unsigned short* __restrict__ Ko,
                                               unsigned short* __restrict__ Vto) {
  __shared__ unsigned short ldsA[128 * 32];
  __shared__ unsigned short ldsB[128 * 32];
  int tid = threadIdx.x;
  int w = tid >> 6, lane = tid & 63;
  int lm = lane & 15, q = lane >> 4;
  int wm = w & 1, wn = w >> 1;
  int m0 = blockIdx.y * 128, n0 = blockIdx.x * 128;

  int row0, row1, kbg0, kbg1;
  {
    int o = w * 2048 + lane * 16;
    row0 = o >> 6; kbg0 = ((o >> 4) & 3) ^ ((row0 >> 1) & 3);
    o += 1024;
    row1 = o >> 6; kbg1 = ((o >> 4) & 3) ^ ((row1 >> 1) & 3);
  }
  const unsigned short* pa0 = A  + (size_t)(m0 + row0) * K + kbg0 * 8;
  const unsigned short* pa1 = A  + (size_t)(m0 + row1) * K + kbg1 * 8;
  const unsigned short* pb0 = Bt + (size_t)(n0 + row0) * K + kbg0 * 8;
  const unsigned short* pb1 = Bt + (size_t)(n0 + row1) * K + kbg1 * 8;
  unsigned short* la0 = ldsA + w * 1024;
  unsigned short* la1 = ldsA + w * 1024 + 512;
  unsigned short* lb0 = ldsB + w * 1024;
  unsigned short* lb1 = ldsB + w * 1024 + 512;

  f32x4 acc[4][4] = {};
  int s = (lm >> 1) & 3;
  int aoff[4], boff[4];
#pragma unroll
  for (int t = 0; t < 4; t++) {
    aoff[t] = ((wm * 64 + t * 16 + lm) << 5) + ((q ^ s) << 3);
    boff[t] = ((wn * 64 + t * 16 + lm) << 5) + ((q ^ s) << 3);
  }

  for (int k0 = 0; k0 < K; k0 += 32) {
    GLL16(pa0 + k0, la0);
    GLL16(pa1 + k0, la1);
    GLL16(pb0 + k0, lb0);
    GLL16(pb1 + k0, lb1);
    __syncthreads();
    bf16x8 af[4], bfv[4];
#pragma unroll
    for (int t = 0; t < 4; t++) af[t] = *(const bf16x8*)(ldsA + aoff[t]);
#pragma unroll
    for (int t = 0; t < 4; t++) bfv[t] = *(const bf16x8*)(ldsB + boff[t]);
#pragma unroll
    for (int mi = 0; mi < 4; mi++)
#pragma unroll
      for (int ni = 0; ni < 4; ni++)
        acc[mi][ni] = __builtin_amdgcn_mfma_f32_16x16x32_bf16(af[mi], bfv[ni], acc[mi][ni], 0, 0, 0);
    __syncthreads();
  }

  if (qkv_mode) {
#pragma unroll
    for (int ni = 0; ni < 4; ni++) {
      int n = n0 + wn * 64 + ni * 16 + lm;
      int region = n >> 11;  // 0=Q, 1=K, 2=V
      int h = (n & 2047) >> 7, d = n & 127;
#pragma unroll
      for (int mi = 0; mi < 4; mi++) {
        int mb = m0 + wm * 64 + mi * 16 + q * 4;
        int b = mb >> 11, t0 = mb & 2047;
        if (region == 2) {
          ushort4 u;
          u.x = f2bf(acc[mi][ni][0]); u.y = f2bf(acc[mi][ni][1]);
          u.z = f2bf(acc[mi][ni][2]); u.w = f2bf(acc[mi][ni][3]);
          *(ushort4*)&Vto[(((size_t)(b * NHEAD + h)) * HEADD + d) * TSEQ + t0] = u;
        } else {
          unsigned short* dst = (region == 0) ? Qo : Ko;
          size_t base2 = (((size_t)(b * NHEAD + h)) * TSEQ + t0) * HEADD + d;
#pragma unroll
          for (int r = 0; r < 4; r++)
            dst[base2 + (size_t)r * HEADD] = f2bf(acc[mi][ni][r]);
        }
      }
    }
    return;
  }

#pragma unroll
  for (int ni = 0; ni < 4; ni++) {
    int n = n0 + wn * 64 + ni * 16 + lm;
    float bv = bias ? bias[n] : 0.f;
#pragma unroll
    for (int mi = 0; mi < 4; mi++) {
#pragma unroll
      for (int r = 0; r < 4; r++) {
        int m = m0 + wm * 64 + mi * 16 + q * 4 + r;
        float v = acc[mi][ni][r] + bv;
        if (act_gelu) v = gelu_tanh_f(v);
        if (resid) v += resid[(size_t)m * N + n];
        if (Cb) Cb[(size_t)m * N + n] = f2bf(v);
        else Cf[(size_t)m * N + n] = v;
      }
    }
  }
}

// ---------------- MFMA flash attention: BQ=64, BK=64, D=128, bf16 in/out ----------------
// Q,K: [b,h,t,d]; Vt: [b,h,d,t]. Out: attnO[b,t, h*128+d] bf16.
__global__ __launch_bounds__(256, 4) void attn_mfma(const unsigned short* __restrict__ Qb,
                                                    const unsigned short* __restrict__ Kb,
                                                    const unsigned short* __restrict__ Vtb,
                                                    unsigned short* __restrict__ O) {
  __shared__ unsigned short ldsK[64 * 128];  // 16 KB: row=key(64), 16 x 16B chunks, pos^=(key&15)
  __shared__ unsigned short ldsV[128 * 64];  // 16 KB: row=d(128),  8 x 16B chunks, pos^=(d&7)
  __shared__ unsigned short ldsP[64 * 64];   //  8 KB: row=qrow(64), 8 x 16B chunks, pos^=(row&7)

  int tid = threadIdx.x;
  int w = tid >> 6, lane = tid & 63;
  int lm = lane & 15, qd = lane >> 4;
  int qt = blockIdx.x, hh = blockIdx.y, bb = blockIdx.z;
  int q0 = qt * 64;
  size_t hbase = (size_t)(bb * NHEAD + hh) * (size_t)(TSEQ * HEADD);
  const unsigned short* Qh = Qb + hbase;
  const unsigned short* Kh = Kb + hbase;
  const unsigned short* Vh = Vtb + hbase;

  // Q strip: wave w owns q-rows q0+w*16 .. +15, as 4 A-frags (k=d chunks of 32)
  bf16x8 qf[4];
  {
    const unsigned short* qp = Qh + (size_t)(q0 + w * 16 + lm) * HEADD + qd * 8;
#pragma unroll
    for (int kc = 0; kc < 4; kc++) qf[kc] = *(const bf16x8*)(qp + kc * 32);
  }

  // staging address precompute (4 chunk-loads each for K and Vt per thread)
  int koff[4], voff[4], ldst[4];
#pragma unroll
  for (int it = 0; it < 4; it++) {
    int ci = it * 256 + w * 64 + lane;
    int key = ci >> 4, pos = ci & 15;
    koff[it] = key * HEADD + ((pos ^ (key & 15)) << 3);
    int d = ci >> 3, pv = ci & 7;
    voff[it] = d * TSEQ + ((pv ^ (d & 7)) << 3);
    ldst[it] = (it * 256 + w * 64) * 8;  // ushort index of wave-uniform LDS base
  }

  f32x4 oacc[8] = {};
  float mrow[4], lrow[4];
#pragma unroll
  for (int r = 0; r < 4; r++) { mrow[r] = -3.0e38f; lrow[r] = 0.f; }
  const float scl = 0.08838834764831845f;  // 1/sqrt(128)

  for (int kt = 0; kt <= qt; kt++) {
    int k0 = kt * 64;
    __syncthreads();  // prior PV reads of ldsV done before overwrite
#pragma unroll
    for (int it = 0; it < 4; it++) {
      GLL16(Kh + (size_t)k0 * HEADD + koff[it], ldsK + ldst[it]);
      GLL16(Vh + k0 + voff[it], ldsV + ldst[it]);
    }
    __syncthreads();  // staging complete (vmcnt drained by barrier semantics)

    // S = Q @ K^T : sacc[kb] covers keys k0+kb*16..+15, q-rows w*16+qd*4+r
    f32x4 sacc[4] = {};
#pragma unroll
    for (int kb = 0; kb < 4; kb++) {
#pragma unroll
      for (int kc = 0; kc < 4; kc++) {
        bf16x8 kf = *(const bf16x8*)(ldsK + (kb * 16 + lm) * HEADD + (((kc * 4 + qd) ^ lm) << 3));
        sacc[kb] = __builtin_amdgcn_mfma_f32_16x16x32_bf16(qf[kc], kf, sacc[kb], 0, 0, 0);
      }
    }

    // online softmax (per-lane rows qd*4+r, cols lm of each kb tile)
    float sv[4][4];
    int qrow_g = q0 + w * 16 + qd * 4;
    bool diag = (kt == qt);
#pragma unroll
    for (int kb = 0; kb < 4; kb++) {
      int key_g = k0 + kb * 16 + lm;
#pragma unroll
      for (int r = 0; r < 4; r++) {
        float x = sacc[kb][r] * scl;
        sv[kb][r] = (diag && key_g > qrow_g + r) ? -3.0e38f : x;
      }
    }
    float mloc[4];
#pragma unroll
    for (int r = 0; r < 4; r++)
      mloc[r] = fmaxf(fmaxf(sv[0][r], sv[1][r]), fmaxf(sv[2][r], sv[3][r]));
#pragma unroll
    for (int dm = 1; dm < 16; dm <<= 1)
#pragma unroll
      for (int r = 0; r < 4; r++) mloc[r] = fmaxf(mloc[r], __shfl_xor(mloc[r], dm));
    float al[4], lloc[4];
#pragma unroll
    for (int r = 0; r < 4; r++) {
      float mnew = fmaxf(mrow[r], mloc[r]);
      al[r] = __expf(mrow[r] - mnew);
      mrow[r] = mnew;
      lloc[r] = 0.f;
    }
    // P = exp(S - m) -> bf16 LDS (swizzled); each wave writes only its own 16 rows
#pragma unroll
    for (int kb = 0; kb < 4; kb++) {
#pragma unroll
      for (int r = 0; r < 4; r++) {
        float p = __expf(sv[kb][r] - mrow[r]);
        lloc[r] += p;
        int row = w * 16 + qd * 4 + r;
        int chunk = (kb * 2 + (lm >> 3)) ^ (row & 7);
        ldsP[row * 64 + chunk * 8 + (lm & 7)] = f2bf(p);
      }
    }
#pragma unroll
    for (int dm = 1; dm < 16; dm <<= 1)
#pragma unroll
      for (int r = 0; r < 4; r++) lloc[r] += __shfl_xor(lloc[r], dm);
#pragma unroll
    for (int r = 0; r < 4; r++) lrow[r] = lrow[r] * al[r] + lloc[r];
    // rescale O
#pragma unroll
    for (int dt = 0; dt < 8; dt++)
#pragma unroll
      for (int r = 0; r < 4; r++) oacc[dt][r] *= al[r];

    // PV: O[16 x 128] += P[16 x 64] @ V[64 x 128]; A=P (own rows), B=Vt rows=d
    bf16x8 pf[2];
#pragma unroll
    for (int kc2 = 0; kc2 < 2; kc2++)
      pf[kc2] = *(const bf16x8*)(ldsP + (w * 16 + lm) * 64 + (((kc2 * 4 + qd) ^ (lm & 7)) << 3));
#pragma unroll
    for (int dt = 0; dt < 8; dt++) {
#pragma unroll
      for (int kc2 = 0; kc2 < 2; kc2++) {
        bf16x8 vf = *(const bf16x8*)(ldsV + (dt * 16 + lm) * 64 + (((kc2 * 4 + qd) ^ (lm & 7)) << 3));
        oacc[dt] = __builtin_amdgcn_mfma_f32_16x16x32_bf16(pf[kc2], vf, oacc[dt], 0, 0, 0);
      }
    }
  }

  // epilogue: O /= l, write bf16 to [b, t, h*128 + d]
  float inv[4];
#pragma unroll
  for (int r = 0; r < 4; r++) inv[r] = 1.f / lrow[r];
#pragma unroll
  for (int dt = 0; dt < 8; dt++) {
#pragma unroll
    for (int r = 0; r < 4; r++) {
      int t = q0 + w * 16 + qd * 4 + r;
      size_t idx = ((size_t)(bb * TSEQ + t)) * HDIM + hh * HEADD + dt * 16 + lm;
      O[idx] = f2bf(oacc[dt][r] * inv[r]);
    }
  }
}

// ---------------- launch ----------------
extern "C" void kernel_launch(void* const* d_in, const int* in_sizes, int n_in,
                              void* d_out, int out_size, void* d_ws, size_t ws_size,
                              hipStream_t stream) {
  const float* x         = (const float*)d_in[0];
  const float* wq        = (const float*)d_in[1];
  const float* wk        = (const float*)d_in[2];
  const float* wv        = (const float*)d_in[3];
  const float* wo        = (const float*)d_in[4];
  const float* ln1_scale = (const float*)d_in[5];
  const float* ln1_shift = (const float*)d_in[6];
  const float* ln2_scale = (const float*)d_in[7];
  const float* ln2_shift = (const float*)d_in[8];
  const float* w1        = (const float*)d_in[9];
  const float* b1        = (const float*)d_in[10];
  const float* w2        = (const float*)d_in[11];
  const float* b2        = (const float*)d_in[12];

  char* ws = (char*)d_ws;
  const size_t MB = 1ull << 20;
  // [0,16)   h1 bf16 (dead after QKV GEMM)
  // [0,32)   x2 fp32 (written at proj, lives to end)
  // [32,48)  Qb | [48,64) Kb | [64,80) Vtb  (dead after attn... after proj for none; attn only)
  // [80,96)  attnO bf16 (dead after proj)
  // [96,104) woT | [104,128) wqT|wkT|wvT contiguous (dead after their GEMMs)
  // [32,96)  a1 bf16 (FFN1 out, after attn buffers dead)
  // [96,112) h2 bf16 (after woT/wqT dead)
  // [128,160) w1T | [160,192) w2T
  unsigned short* h1    = (unsigned short*)(ws);
  float*          x2    = (float*)(ws);
  unsigned short* Qb    = (unsigned short*)(ws + 32 * MB);
  unsigned short* Kb    = (unsigned short*)(ws + 48 * MB);
  unsigned short* Vtb   = (unsigned short*)(ws + 64 * MB);
  unsigned short* attnO = (unsigned short*)(ws + 80 * MB);
  unsigned short* woT   = (unsigned short*)(ws + 96 * MB);
  unsigned short* qkvT  = (unsigned short*)(ws + 104 * MB);  // [6144][2048]
  unsigned short* a1    = (unsigned short*)(ws + 32 * MB);
  unsigned short* h2    = (unsigned short*)(ws + 96 * MB);
  unsigned short* w1T   = (unsigned short*)(ws + 128 * MB);
  unsigned short* w2T   = (unsigned short*)(ws + 160 * MB);

  dim3 blk(256);
  ln_kernel<<<NTOK, blk, 0, stream>>>(x, ln1_scale, ln1_shift, h1);
  castT_kernel<<<dim3(32, 32), blk, 0, stream>>>(wq, qkvT, 2048, 2048);
  castT_kernel<<<dim3(32, 32), blk, 0, stream>>>(wk, qkvT + (size_t)2048 * 2048, 2048, 2048);
  castT_kernel<<<dim3(32, 32), blk, 0, stream>>>(wv, qkvT + (size_t)4096 * 2048, 2048, 2048);
  castT_kernel<<<dim3(32, 32), blk, 0, stream>>>(wo, woT, 2048, 2048);
  castT_kernel<<<dim3(32, 128), blk, 0, stream>>>(w1, w1T, 2048, 8192);
  castT_kernel<<<dim3(128, 32), blk, 0, stream>>>(w2, w2T, 8192, 2048);
  // QKV GEMM with per-head scatter epilogue (Q, K natural; Vt transposed)
  gemm_bt<<<dim3(6144 / 128, 4096 / 128), blk, 0, stream>>>(
      h1, qkvT, nullptr, nullptr, nullptr, nullptr, 4096, 6144, 2048, 0, 1, Qb, Kb, Vtb);
  // MFMA flash attention
  attn_mfma<<<dim3(TSEQ / 64, NHEAD, NBATCH), blk, 0, stream>>>(Qb, Kb, Vtb, attnO);
  // proj: x2 = attnO @ wo + x  (fp32 out)
  gemm_bt<<<dim3(2048 / 128, 4096 / 128), blk, 0, stream>>>(
      attnO, woT, x2, nullptr, nullptr, x, 4096, 2048, 2048, 0, 0, nullptr, nullptr, nullptr);
  ln_kernel<<<NTOK, blk, 0, stream>>>(x2, ln2_scale, ln2_shift, h2);
  // FFN1: a1 = gelu(h2 @ w1 + b1), bf16 out
  gemm_bt<<<dim3(8192 / 128, 4096 / 128), blk, 0, stream>>>(
      h2, w1T, nullptr, a1, b1, nullptr, 4096, 8192, 2048, 1, 0, nullptr, nullptr, nullptr);
  // FFN2: out = a1 @ w2 + b2 + x2  (fp32 out)
  gemm_bt<<<dim3(2048 / 128, 4096 / 128), blk, 0, stream>>>(
      a1, w2T, (float*)d_out, nullptr, b2, x2, 4096, 2048, 8192, 0, 0, nullptr, nullptr, nullptr);
}

// Round 4
// 1077.104 us; speedup vs baseline: 7.7165x; 1.0171x over previous
//
#include <hip/hip_runtime.h>
#include <math.h>

#define HDIM 2048
#define NTOK 4096
#define NHEAD 16
#define HEADD 128
#define TSEQ 2048
#define NBATCH 2

typedef float f32x4 __attribute__((ext_vector_type(4)));
typedef short bf16x8 __attribute__((ext_vector_type(8)));

__device__ __forceinline__ unsigned short f2bf(float f) {
  union { float f; unsigned u; } v; v.f = f;
  unsigned r = v.u + 0x7FFFu + ((v.u >> 16) & 1u);
  return (unsigned short)(r >> 16);
}

__device__ __forceinline__ float gelu_tanh_f(float x) {
  float z = 0.7978845608028654f * (x + 0.044715f * x * x * x);
  float e = __expf(2.f * z);
  float th = 1.f - 2.f / (e + 1.f);
  return 0.5f * x * (1.f + th);
}

#define GLL16(g, l) __builtin_amdgcn_global_load_lds( \
    (const __attribute__((address_space(1))) unsigned int*)(g), \
    (__attribute__((address_space(3))) unsigned int*)(l), 16, 0, 0)

// ---------------- LayerNorm: fp32 in, bf16 out. one block per token ----------------
__global__ __launch_bounds__(256) void ln_kernel(const float* __restrict__ in,
                                                 const float* __restrict__ scale,
                                                 const float* __restrict__ shift,
                                                 unsigned short* __restrict__ out) {
  int row = blockIdx.x;
  int t = threadIdx.x;
  const float4* r4 = (const float4*)(in + (size_t)row * HDIM);
  float4 v0 = r4[t];
  float4 v1 = r4[t + 256];
  float sum = v0.x + v0.y + v0.z + v0.w + v1.x + v1.y + v1.z + v1.w;
  float sq  = v0.x*v0.x + v0.y*v0.y + v0.z*v0.z + v0.w*v0.w +
              v1.x*v1.x + v1.y*v1.y + v1.z*v1.z + v1.w*v1.w;
  for (int o = 32; o > 0; o >>= 1) {
    sum += __shfl_down(sum, o);
    sq  += __shfl_down(sq, o);
  }
  __shared__ float red[8];
  __shared__ float stat[2];
  int lane = t & 63, w = t >> 6;
  if (lane == 0) { red[w] = sum; red[4 + w] = sq; }
  __syncthreads();
  if (t == 0) {
    float s = red[0] + red[1] + red[2] + red[3];
    float q = red[4] + red[5] + red[6] + red[7];
    float mean = s / HDIM;
    float var = q / HDIM - mean * mean;
    stat[0] = mean;
    stat[1] = rsqrtf(var + 1e-5f);
  }
  __syncthreads();
  float mean = stat[0], rstd = stat[1];
  const float4* sc4 = (const float4*)scale;
  const float4* sh4 = (const float4*)shift;
  float4 s0 = sc4[t], s1 = sc4[t + 256];
  float4 h0 = sh4[t], h1 = sh4[t + 256];
  ushort4 a, b;
  a.x = f2bf(s0.x * ((v0.x - mean) * rstd) + h0.x);
  a.y = f2bf(s0.y * ((v0.y - mean) * rstd) + h0.y);
  a.z = f2bf(s0.z * ((v0.z - mean) * rstd) + h0.z);
  a.w = f2bf(s0.w * ((v0.w - mean) * rstd) + h0.w);
  b.x = f2bf(s1.x * ((v1.x - mean) * rstd) + h1.x);
  b.y = f2bf(s1.y * ((v1.y - mean) * rstd) + h1.y);
  b.z = f2bf(s1.z * ((v1.z - mean) * rstd) + h1.z);
  b.w = f2bf(s1.w * ((v1.w - mean) * rstd) + h1.w);
  *(ushort4*)&out[(size_t)row * HDIM + t * 4] = a;
  *(ushort4*)&out[(size_t)row * HDIM + 1024 + t * 4] = b;
}

// ---------------- cast + transpose: W[K,N] fp32 -> Wt[N,K] bf16 ----------------
__global__ __launch_bounds__(256) void castT_kernel(const float* __restrict__ W,
                                                    unsigned short* __restrict__ Wt,
                                                    int K, int N) {
  __shared__ float T[64][65];
  int k0 = blockIdx.x * 64, n0 = blockIdx.y * 64;
  int c = threadIdx.x & 15, r = threadIdx.x >> 4;
#pragma unroll
  for (int p = 0; p < 4; p++) {
    int kr = r + p * 16;
    float4 v = *(const float4*)&W[(size_t)(k0 + kr) * N + n0 + c * 4];
    T[kr][c * 4 + 0] = v.x; T[kr][c * 4 + 1] = v.y;
    T[kr][c * 4 + 2] = v.z; T[kr][c * 4 + 3] = v.w;
  }
  __syncthreads();
#pragma unroll
  for (int p = 0; p < 4; p++) {
    int nr = r + p * 16;
    ushort4 o;
    o.x = f2bf(T[c * 4 + 0][nr]);
    o.y = f2bf(T[c * 4 + 1][nr]);
    o.z = f2bf(T[c * 4 + 2][nr]);
    o.w = f2bf(T[c * 4 + 3][nr]);
    *(ushort4*)&Wt[(size_t)(n0 + nr) * K + k0 + c * 4] = o;
  }
}

// ---------------- bf16 MFMA GEMM: C[M,N] = A[M,K] @ Bt[N,K]^T ----------------
// XCD-aware swizzle: flat block id -> (xcd = id&7, local); each XCD owns a
// compact rm x rn tile rectangle (rm*rn == grid/8) for per-XCD L2 reuse.
__global__ __launch_bounds__(256) void gemm_bt(const unsigned short* __restrict__ A,
                                               const unsigned short* __restrict__ Bt,
                                               float* __restrict__ Cf,
                                               unsigned short* __restrict__ Cb,
                                               const float* __restrict__ bias,
                                               const float* __restrict__ resid,
                                               int M, int N, int K, int act_gelu,
                                               int qkv_mode,
                                               unsigned short* __restrict__ Qo,
                                               unsigned short* __restrict__ Ko,
                                               unsigned short* __restrict__ Vto,
                                               int rm, int rn, int xc) {
  __shared__ unsigned short ldsA[128 * 32];
  __shared__ unsigned short ldsB[128 * 32];
  int tid = threadIdx.x;
  int w = tid >> 6, lane = tid & 63;
  int lm = lane & 15, q = lane >> 4;
  int wm = w & 1, wn = w >> 1;

  int flat = blockIdx.y * gridDim.x + blockIdx.x;
  int xcd = flat & 7, l = flat >> 3;
  int tn_l = l % rn, tm_l = l / rn;
  int tm = (xcd / xc) * rm + tm_l;
  int tn = (xcd % xc) * rn + tn_l;
  int m0 = tm * 128, n0 = tn * 128;

  int row0, row1, kbg0, kbg1;
  {
    int o = w * 2048 + lane * 16;
    row0 = o >> 6; kbg0 = ((o >> 4) & 3) ^ ((row0 >> 1) & 3);
    o += 1024;
    row1 = o >> 6; kbg1 = ((o >> 4) & 3) ^ ((row1 >> 1) & 3);
  }
  const unsigned short* pa0 = A  + (size_t)(m0 + row0) * K + kbg0 * 8;
  const unsigned short* pa1 = A  + (size_t)(m0 + row1) * K + kbg1 * 8;
  const unsigned short* pb0 = Bt + (size_t)(n0 + row0) * K + kbg0 * 8;
  const unsigned short* pb1 = Bt + (size_t)(n0 + row1) * K + kbg1 * 8;
  unsigned short* la0 = ldsA + w * 1024;
  unsigned short* la1 = ldsA + w * 1024 + 512;
  unsigned short* lb0 = ldsB + w * 1024;
  unsigned short* lb1 = ldsB + w * 1024 + 512;

  f32x4 acc[4][4] = {};
  int s = (lm >> 1) & 3;
  int aoff[4], boff[4];
#pragma unroll
  for (int t = 0; t < 4; t++) {
    aoff[t] = ((wm * 64 + t * 16 + lm) << 5) + ((q ^ s) << 3);
    boff[t] = ((wn * 64 + t * 16 + lm) << 5) + ((q ^ s) << 3);
  }

  for (int k0 = 0; k0 < K; k0 += 32) {
    GLL16(pa0 + k0, la0);
    GLL16(pa1 + k0, la1);
    GLL16(pb0 + k0, lb0);
    GLL16(pb1 + k0, lb1);
    __syncthreads();
    bf16x8 af[4], bfv[4];
#pragma unroll
    for (int t = 0; t < 4; t++) af[t] = *(const bf16x8*)(ldsA + aoff[t]);
#pragma unroll
    for (int t = 0; t < 4; t++) bfv[t] = *(const bf16x8*)(ldsB + boff[t]);
#pragma unroll
    for (int mi = 0; mi < 4; mi++)
#pragma unroll
      for (int ni = 0; ni < 4; ni++)
        acc[mi][ni] = __builtin_amdgcn_mfma_f32_16x16x32_bf16(af[mi], bfv[ni], acc[mi][ni], 0, 0, 0);
    __syncthreads();
  }

  if (qkv_mode) {
#pragma unroll
    for (int ni = 0; ni < 4; ni++) {
      int n = n0 + wn * 64 + ni * 16 + lm;
      int region = n >> 11;  // 0=Q, 1=K, 2=V
      int h = (n & 2047) >> 7, d = n & 127;
#pragma unroll
      for (int mi = 0; mi < 4; mi++) {
        int mb = m0 + wm * 64 + mi * 16 + q * 4;
        int b = mb >> 11, t0 = mb & 2047;
        if (region == 2) {
          ushort4 u;
          u.x = f2bf(acc[mi][ni][0]); u.y = f2bf(acc[mi][ni][1]);
          u.z = f2bf(acc[mi][ni][2]); u.w = f2bf(acc[mi][ni][3]);
          *(ushort4*)&Vto[(((size_t)(b * NHEAD + h)) * HEADD + d) * TSEQ + t0] = u;
        } else {
          unsigned short* dst = (region == 0) ? Qo : Ko;
          size_t base2 = (((size_t)(b * NHEAD + h)) * TSEQ + t0) * HEADD + d;
#pragma unroll
          for (int r = 0; r < 4; r++)
            dst[base2 + (size_t)r * HEADD] = f2bf(acc[mi][ni][r]);
        }
      }
    }
    return;
  }

#pragma unroll
  for (int ni = 0; ni < 4; ni++) {
    int n = n0 + wn * 64 + ni * 16 + lm;
    float bv = bias ? bias[n] : 0.f;
#pragma unroll
    for (int mi = 0; mi < 4; mi++) {
#pragma unroll
      for (int r = 0; r < 4; r++) {
        int m = m0 + wm * 64 + mi * 16 + q * 4 + r;
        float v = acc[mi][ni][r] + bv;
        if (act_gelu) v = gelu_tanh_f(v);
        if (resid) v += resid[(size_t)m * N + n];
        if (Cb) Cb[(size_t)m * N + n] = f2bf(v);
        else Cf[(size_t)m * N + n] = v;
      }
    }
  }
}

// ---------------- MFMA flash attention: BQ=64, BK=64, D=128, bf16 in/out ----------------
__global__ __launch_bounds__(256, 4) void attn_mfma(const unsigned short* __restrict__ Qb,
                                                    const unsigned short* __restrict__ Kb,
                                                    const unsigned short* __restrict__ Vtb,
                                                    unsigned short* __restrict__ O) {
  __shared__ unsigned short ldsK[64 * 128];
  __shared__ unsigned short ldsV[128 * 64];
  __shared__ unsigned short ldsP[64 * 64];

  int tid = threadIdx.x;
  int w = tid >> 6, lane = tid & 63;
  int lm = lane & 15, qd = lane >> 4;
  int qt = blockIdx.x, hh = blockIdx.y, bb = blockIdx.z;
  int q0 = qt * 64;
  size_t hbase = (size_t)(bb * NHEAD + hh) * (size_t)(TSEQ * HEADD);
  const unsigned short* Qh = Qb + hbase;
  const unsigned short* Kh = Kb + hbase;
  const unsigned short* Vh = Vtb + hbase;

  bf16x8 qf[4];
  {
    const unsigned short* qp = Qh + (size_t)(q0 + w * 16 + lm) * HEADD + qd * 8;
#pragma unroll
    for (int kc = 0; kc < 4; kc++) qf[kc] = *(const bf16x8*)(qp + kc * 32);
  }

  int koff[4], voff[4], ldst[4];
#pragma unroll
  for (int it = 0; it < 4; it++) {
    int ci = it * 256 + w * 64 + lane;
    int key = ci >> 4, pos = ci & 15;
    koff[it] = key * HEADD + ((pos ^ (key & 15)) << 3);
    int d = ci >> 3, pv = ci & 7;
    voff[it] = d * TSEQ + ((pv ^ (d & 7)) << 3);
    ldst[it] = (it * 256 + w * 64) * 8;
  }

  f32x4 oacc[8] = {};
  float mrow[4], lrow[4];
#pragma unroll
  for (int r = 0; r < 4; r++) { mrow[r] = -3.0e38f; lrow[r] = 0.f; }
  const float scl = 0.08838834764831845f;

  for (int kt = 0; kt <= qt; kt++) {
    int k0 = kt * 64;
    __syncthreads();
#pragma unroll
    for (int it = 0; it < 4; it++) {
      GLL16(Kh + (size_t)k0 * HEADD + koff[it], ldsK + ldst[it]);
      GLL16(Vh + k0 + voff[it], ldsV + ldst[it]);
    }
    __syncthreads();

    f32x4 sacc[4] = {};
#pragma unroll
    for (int kb = 0; kb < 4; kb++) {
#pragma unroll
      for (int kc = 0; kc < 4; kc++) {
        bf16x8 kf = *(const bf16x8*)(ldsK + (kb * 16 + lm) * HEADD + (((kc * 4 + qd) ^ lm) << 3));
        sacc[kb] = __builtin_amdgcn_mfma_f32_16x16x32_bf16(qf[kc], kf, sacc[kb], 0, 0, 0);
      }
    }

    float sv[4][4];
    int qrow_g = q0 + w * 16 + qd * 4;
    bool diag = (kt == qt);
#pragma unroll
    for (int kb = 0; kb < 4; kb++) {
      int key_g = k0 + kb * 16 + lm;
#pragma unroll
      for (int r = 0; r < 4; r++) {
        float x = sacc[kb][r] * scl;
        sv[kb][r] = (diag && key_g > qrow_g + r) ? -3.0e38f : x;
      }
    }
    float mloc[4];
#pragma unroll
    for (int r = 0; r < 4; r++)
      mloc[r] = fmaxf(fmaxf(sv[0][r], sv[1][r]), fmaxf(sv[2][r], sv[3][r]));
#pragma unroll
    for (int dm = 1; dm < 16; dm <<= 1)
#pragma unroll
      for (int r = 0; r < 4; r++) mloc[r] = fmaxf(mloc[r], __shfl_xor(mloc[r], dm));
    float al[4], lloc[4];
#pragma unroll
    for (int r = 0; r < 4; r++) {
      float mnew = fmaxf(mrow[r], mloc[r]);
      al[r] = __expf(mrow[r] - mnew);
      mrow[r] = mnew;
      lloc[r] = 0.f;
    }
#pragma unroll
    for (int kb = 0; kb < 4; kb++) {
#pragma unroll
      for (int r = 0; r < 4; r++) {
        float p = __expf(sv[kb][r] - mrow[r]);
        lloc[r] += p;
        int row = w * 16 + qd * 4 + r;
        int chunk = (kb * 2 + (lm >> 3)) ^ (row & 7);
        ldsP[row * 64 + chunk * 8 + (lm & 7)] = f2bf(p);
      }
    }
#pragma unroll
    for (int dm = 1; dm < 16; dm <<= 1)
#pragma unroll
      for (int r = 0; r < 4; r++) lloc[r] += __shfl_xor(lloc[r], dm);
#pragma unroll
    for (int r = 0; r < 4; r++) lrow[r] = lrow[r] * al[r] + lloc[r];
#pragma unroll
    for (int dt = 0; dt < 8; dt++)
#pragma unroll
      for (int r = 0; r < 4; r++) oacc[dt][r] *= al[r];

    bf16x8 pf[2];
#pragma unroll
    for (int kc2 = 0; kc2 < 2; kc2++)
      pf[kc2] = *(const bf16x8*)(ldsP + (w * 16 + lm) * 64 + (((kc2 * 4 + qd) ^ (lm & 7)) << 3));
#pragma unroll
    for (int dt = 0; dt < 8; dt++) {
#pragma unroll
      for (int kc2 = 0; kc2 < 2; kc2++) {
        bf16x8 vf = *(const bf16x8*)(ldsV + (dt * 16 + lm) * 64 + (((kc2 * 4 + qd) ^ (lm & 7)) << 3));
        oacc[dt] = __builtin_amdgcn_mfma_f32_16x16x32_bf16(pf[kc2], vf, oacc[dt], 0, 0, 0);
      }
    }
  }

  float inv[4];
#pragma unroll
  for (int r = 0; r < 4; r++) inv[r] = 1.f / lrow[r];
#pragma unroll
  for (int dt = 0; dt < 8; dt++) {
#pragma unroll
    for (int r = 0; r < 4; r++) {
      int t = q0 + w * 16 + qd * 4 + r;
      size_t idx = ((size_t)(bb * TSEQ + t)) * HDIM + hh * HEADD + dt * 16 + lm;
      O[idx] = f2bf(oacc[dt][r] * inv[r]);
    }
  }
}

// ---------------- launch ----------------
extern "C" void kernel_launch(void* const* d_in, const int* in_sizes, int n_in,
                              void* d_out, int out_size, void* d_ws, size_t ws_size,
                              hipStream_t stream) {
  const float* x         = (const float*)d_in[0];
  const float* wq        = (const float*)d_in[1];
  const float* wk        = (const float*)d_in[2];
  const float* wv        = (const float*)d_in[3];
  const float* wo        = (const float*)d_in[4];
  const float* ln1_scale = (const float*)d_in[5];
  const float* ln1_shift = (const float*)d_in[6];
  const float* ln2_scale = (const float*)d_in[7];
  const float* ln2_shift = (const float*)d_in[8];
  const float* w1        = (const float*)d_in[9];
  const float* b1        = (const float*)d_in[10];
  const float* w2        = (const float*)d_in[11];
  const float* b2        = (const float*)d_in[12];

  char* ws = (char*)d_ws;
  const size_t MB = 1ull << 20;
  unsigned short* h1    = (unsigned short*)(ws);
  float*          x2    = (float*)(ws);
  unsigned short* Qb    = (unsigned short*)(ws + 32 * MB);
  unsigned short* Kb    = (unsigned short*)(ws + 48 * MB);
  unsigned short* Vtb   = (unsigned short*)(ws + 64 * MB);
  unsigned short* attnO = (unsigned short*)(ws + 80 * MB);
  unsigned short* woT   = (unsigned short*)(ws + 96 * MB);
  unsigned short* qkvT  = (unsigned short*)(ws + 104 * MB);
  unsigned short* a1    = (unsigned short*)(ws + 32 * MB);
  unsigned short* h2    = (unsigned short*)(ws + 96 * MB);
  unsigned short* w1T   = (unsigned short*)(ws + 128 * MB);
  unsigned short* w2T   = (unsigned short*)(ws + 160 * MB);

  dim3 blk(256);
  ln_kernel<<<NTOK, blk, 0, stream>>>(x, ln1_scale, ln1_shift, h1);
  castT_kernel<<<dim3(32, 32), blk, 0, stream>>>(wq, qkvT, 2048, 2048);
  castT_kernel<<<dim3(32, 32), blk, 0, stream>>>(wk, qkvT + (size_t)2048 * 2048, 2048, 2048);
  castT_kernel<<<dim3(32, 32), blk, 0, stream>>>(wv, qkvT + (size_t)4096 * 2048, 2048, 2048);
  castT_kernel<<<dim3(32, 32), blk, 0, stream>>>(wo, woT, 2048, 2048);
  castT_kernel<<<dim3(32, 128), blk, 0, stream>>>(w1, w1T, 2048, 8192);
  castT_kernel<<<dim3(128, 32), blk, 0, stream>>>(w2, w2T, 8192, 2048);
  // QKV: grid 48x32 -> xr=2,xc=4: rect rm=16, rn=12
  gemm_bt<<<dim3(6144 / 128, 4096 / 128), blk, 0, stream>>>(
      h1, qkvT, nullptr, nullptr, nullptr, nullptr, 4096, 6144, 2048, 0, 1, Qb, Kb, Vtb,
      16, 12, 4);
  attn_mfma<<<dim3(TSEQ / 64, NHEAD, NBATCH), blk, 0, stream>>>(Qb, Kb, Vtb, attnO);
  // proj: grid 16x32 -> xr=4,xc=2: rect rm=8, rn=8
  gemm_bt<<<dim3(2048 / 128, 4096 / 128), blk, 0, stream>>>(
      attnO, woT, x2, nullptr, nullptr, x, 4096, 2048, 2048, 0, 0, nullptr, nullptr, nullptr,
      8, 8, 2);
  ln_kernel<<<NTOK, blk, 0, stream>>>(x2, ln2_scale, ln2_shift, h2);
  // FFN1: grid 64x32 -> xr=2,xc=4: rect rm=16, rn=16
  gemm_bt<<<dim3(8192 / 128, 4096 / 128), blk, 0, stream>>>(
      h2, w1T, nullptr, a1, b1, nullptr, 4096, 8192, 2048, 1, 0, nullptr, nullptr, nullptr,
      16, 16, 4);
  // FFN2: grid 16x32 -> xr=4,xc=2: rect rm=8, rn=8
  gemm_bt<<<dim3(2048 / 128, 4096 / 128), blk, 0, stream>>>(
      a1, w2T, (float*)d_out, nullptr, b2, x2, 4096, 2048, 8192, 0, 0, nullptr, nullptr, nullptr,
      8, 8, 2);
}